// Round 1
// baseline (1242.993 us; speedup 1.0000x reference)
//
#include <hip/hip_runtime.h>
#include <hip/hip_bf16.h>
#include <stdint.h>
#include <stddef.h>

// Problem: out[16384,4096] = x[16384,4096] @ W[4096,4096] + bias
// W = (kron(L0,R0) + kron(L1,R1) + kron(L2,R2)) / 3
// Plan: build W^T bf16 + x bf16 in d_ws, then m97-style bf16 MFMA GEMM.

#define M_TOT 16384
#define N_TOT 4096
#define K_TOT 4096

#define BM 128
#define BN 128
#define BK 64

typedef __attribute__((ext_vector_type(8))) short short8;
typedef __attribute__((ext_vector_type(4))) float floatx4;
typedef __attribute__((ext_vector_type(4))) float f32x4;
typedef __attribute__((ext_vector_type(8))) unsigned short ushort8;

__device__ __forceinline__ unsigned short f2bf(float f) {
    unsigned int u = __float_as_uint(f);
    u += 0x7FFFu + ((u >> 16) & 1u);   // round-to-nearest-even
    return (unsigned short)(u >> 16);
}

// ---------------------------------------------------------------------------
// Kernel 1: W^T[n, k] (bf16) from Kronecker factors.
//   factor0: L0 64x64,  R0 64x64   -> k = a*64+c,  n = b*64+d
//   factor1: L1 32x32,  R1 128x128 -> k = a*128+c, n = b*128+d
//   factor2: L2 128x128, R2 32x32  -> k = a*32+c,  n = b*32+d
// ---------------------------------------------------------------------------
__global__ void build_wt(const float* __restrict__ L0, const float* __restrict__ R0,
                         const float* __restrict__ L1, const float* __restrict__ R1,
                         const float* __restrict__ L2, const float* __restrict__ R2,
                         unsigned short* __restrict__ Wt) {
    int idx = blockIdx.x * 256 + threadIdx.x;       // n*4096 + k, k contiguous
    int k = idx & (K_TOT - 1);
    int n = idx >> 12;
    float w0 = L0[(k >> 6) * 64 + (n >> 6)]  * R0[(k & 63)  * 64  + (n & 63)];
    float w1 = L1[(k >> 7) * 32 + (n >> 7)]  * R1[(k & 127) * 128 + (n & 127)];
    float w2 = L2[(k >> 5) * 128 + (n >> 5)] * R2[(k & 31)  * 32  + (n & 31)];
    Wt[idx] = f2bf((w0 + w1 + w2) * (1.0f / 3.0f));
}

// ---------------------------------------------------------------------------
// Kernel 2: x fp32 -> bf16 (8 elems / thread, 16B stores)
// ---------------------------------------------------------------------------
__global__ void convert_x(const float* __restrict__ x, unsigned short* __restrict__ xb) {
    int idx = blockIdx.x * 256 + threadIdx.x;       // one per 8 elements
    const f32x4* xv = (const f32x4*)x;
    f32x4 a = xv[idx * 2 + 0];
    f32x4 b = xv[idx * 2 + 1];
    ushort8 o;
    o[0] = f2bf(a[0]); o[1] = f2bf(a[1]); o[2] = f2bf(a[2]); o[3] = f2bf(a[3]);
    o[4] = f2bf(b[0]); o[5] = f2bf(b[1]); o[6] = f2bf(b[2]); o[7] = f2bf(b[3]);
    ((ushort8*)xb)[idx] = o;
}

// ---------------------------------------------------------------------------
// Kernel 3: GEMM  C = A(bf16)[M,K] * B^T(bf16)[N,K] + bias, C fp32 [M,N]
// m97 recipe: 128x128 tile, BK=64, 256 thr (4 waves, 2x2 of 64x64),
// global_load_lds width=16, 16x16x32 bf16 MFMA, XOR chunk swizzle.
// Swizzle: LDS row r (tile-local), 16B chunk slot c holds global chunk
// c ^ (r&7). global_load_lds writes wave-uniform base + lane*16, so the
// swizzle is applied on the per-lane *global* source address.
// ---------------------------------------------------------------------------
__device__ __forceinline__ void gload16(const void* g, void* l) {
    __builtin_amdgcn_global_load_lds(
        (const __attribute__((address_space(1))) void*)g,
        (__attribute__((address_space(3))) void*)l,
        16, 0, 0);
}

__launch_bounds__(256)
__global__ void gemm_bias(const unsigned short* __restrict__ A,   // [M,K] bf16
                          const unsigned short* __restrict__ B,   // [N,K] bf16 (=W^T)
                          const float* __restrict__ bias,
                          float* __restrict__ C) {
    __shared__ __align__(16) unsigned short As[BM * BK];   // 16 KB, swizzled
    __shared__ __align__(16) unsigned short Bs[BN * BK];   // 16 KB, swizzled

    const int tid  = threadIdx.x;
    const int w    = tid >> 6;       // wave 0..3
    const int lane = tid & 63;

    const int m0 = blockIdx.y * BM;
    const int n0 = blockIdx.x * BN;

    // staging: per instruction s (0..3 per wave), rows 8*(w*4+s)..+8
    const int srow   = lane >> 3;            // 0..7 (row within 8-row group)
    const int schunk = (lane & 7) ^ srow;    // swizzled global 16B-chunk index

    // fragment indices
    const int row16 = lane & 15;
    const int quad  = lane >> 4;
    const int wm = (w & 1) * 64;
    const int wn = (w >> 1) * 64;

    floatx4 acc[4][4];
#pragma unroll
    for (int i = 0; i < 4; ++i)
#pragma unroll
        for (int j = 0; j < 4; ++j) {
            floatx4 z = {0.f, 0.f, 0.f, 0.f};
            acc[i][j] = z;
        }

    for (int k0 = 0; k0 < K_TOT; k0 += BK) {
#pragma unroll
        for (int s = 0; s < 4; ++s) {
            const int g  = w * 4 + s;            // 8-row group 0..15
            const int r  = g * 8 + srow;         // tile-local row 0..127
            const unsigned short* ga = A + (size_t)(m0 + r) * K_TOT + k0 + schunk * 8;
            gload16(ga, (char*)As + g * 1024);
            const unsigned short* gb = B + (size_t)(n0 + r) * K_TOT + k0 + schunk * 8;
            gload16(gb, (char*)Bs + g * 1024);
        }
        __syncthreads();   // compiler emits vmcnt(0) drain before barrier

#pragma unroll
        for (int t = 0; t < 2; ++t) {
            short8 af[4], bfr[4];
#pragma unroll
            for (int i = 0; i < 4; ++i) {
                const int ra = wm + i * 16 + row16;
                const int ca = (t * 4 + quad) ^ (ra & 7);
                af[i]  = *(const short8*)((const char*)As + ra * 128 + ca * 16);
                const int rb = wn + i * 16 + row16;
                const int cb = (t * 4 + quad) ^ (rb & 7);
                bfr[i] = *(const short8*)((const char*)Bs + rb * 128 + cb * 16);
            }
#pragma unroll
            for (int i = 0; i < 4; ++i)
#pragma unroll
                for (int j = 0; j < 4; ++j)
                    acc[i][j] = __builtin_amdgcn_mfma_f32_16x16x32_bf16(
                        af[i], bfr[j], acc[i][j], 0, 0, 0);
        }
        __syncthreads();
    }

    // epilogue: C/D layout col = lane&15, row = quad*4 + reg
#pragma unroll
    for (int j = 0; j < 4; ++j) {
        const int col = n0 + wn + j * 16 + row16;
        const float bv = bias[col];
#pragma unroll
        for (int i = 0; i < 4; ++i) {
            const int rbase = m0 + wm + i * 16 + quad * 4;
#pragma unroll
            for (int r = 0; r < 4; ++r) {
                C[(size_t)(rbase + r) * N_TOT + col] = acc[i][j][r] + bv;
            }
        }
    }
}

// ---------------------------------------------------------------------------
extern "C" void kernel_launch(void* const* d_in, const int* in_sizes, int n_in,
                              void* d_out, int out_size, void* d_ws, size_t ws_size,
                              hipStream_t stream) {
    const float* x    = (const float*)d_in[0];
    const float* L0   = (const float*)d_in[1];
    const float* R0   = (const float*)d_in[2];
    const float* L1   = (const float*)d_in[3];
    const float* R1   = (const float*)d_in[4];
    const float* L2   = (const float*)d_in[5];
    const float* R2   = (const float*)d_in[6];
    const float* bias = (const float*)d_in[7];
    float* out = (float*)d_out;

    // workspace layout: xb [16384*4096 bf16 = 134217728 B] | Wt [4096*4096 bf16 = 33554432 B]
    unsigned short* xb = (unsigned short*)d_ws;
    unsigned short* wt = (unsigned short*)((char*)d_ws + (size_t)134217728);

    build_wt<<<dim3((N_TOT * K_TOT) / 256), dim3(256), 0, stream>>>(L0, R0, L1, R1, L2, R2, wt);
    convert_x<<<dim3((M_TOT * K_TOT) / (256 * 8)), dim3(256), 0, stream>>>(x, xb);
    gemm_bias<<<dim3(N_TOT / BN, M_TOT / BM), dim3(256), 0, stream>>>(xb, wt, bias, out);
}

// Round 2
// 1092.548 us; speedup vs baseline: 1.1377x; 1.1377x over previous
//
#include <hip/hip_runtime.h>
#include <hip/hip_bf16.h>
#include <stdint.h>
#include <stddef.h>

// out[16384,4096] = x[16384,4096] @ W[4096,4096] + bias
// W = (kron(L0,R0) + kron(L1,R1) + kron(L2,R2)) / 3
// R2: 32x32x16 bf16 MFMA (2x2/wave), XCD-aware n-range swizzle.

#define M_TOT 16384
#define N_TOT 4096
#define K_TOT 4096

#define BM 128
#define BN 128
#define BK 64

typedef __attribute__((ext_vector_type(8)))  short  short8;
typedef __attribute__((ext_vector_type(16))) float  floatx16;
typedef __attribute__((ext_vector_type(4)))  float  f32x4;
typedef __attribute__((ext_vector_type(8)))  unsigned short ushort8;

__device__ __forceinline__ unsigned short f2bf(float f) {
    unsigned int u = __float_as_uint(f);
    u += 0x7FFFu + ((u >> 16) & 1u);   // RNE
    return (unsigned short)(u >> 16);
}

// ---------------------------------------------------------------------------
// Kernel 1: W^T[n, k] (bf16) from Kronecker factors.
// ---------------------------------------------------------------------------
__global__ void build_wt(const float* __restrict__ L0, const float* __restrict__ R0,
                         const float* __restrict__ L1, const float* __restrict__ R1,
                         const float* __restrict__ L2, const float* __restrict__ R2,
                         unsigned short* __restrict__ Wt) {
    int idx = blockIdx.x * 256 + threadIdx.x;       // n*4096 + k, k contiguous
    int k = idx & (K_TOT - 1);
    int n = idx >> 12;
    float w0 = L0[(k >> 6) * 64 + (n >> 6)]  * R0[(k & 63)  * 64  + (n & 63)];
    float w1 = L1[(k >> 7) * 32 + (n >> 7)]  * R1[(k & 127) * 128 + (n & 127)];
    float w2 = L2[(k >> 5) * 128 + (n >> 5)] * R2[(k & 31)  * 32  + (n & 31)];
    Wt[idx] = f2bf((w0 + w1 + w2) * (1.0f / 3.0f));
}

// ---------------------------------------------------------------------------
// Kernel 2: x fp32 -> bf16 (8 elems / thread)
// ---------------------------------------------------------------------------
__global__ void convert_x(const float* __restrict__ x, unsigned short* __restrict__ xb) {
    int idx = blockIdx.x * 256 + threadIdx.x;
    const f32x4* xv = (const f32x4*)x;
    f32x4 a = xv[idx * 2 + 0];
    f32x4 b = xv[idx * 2 + 1];
    ushort8 o;
    o[0] = f2bf(a[0]); o[1] = f2bf(a[1]); o[2] = f2bf(a[2]); o[3] = f2bf(a[3]);
    o[4] = f2bf(b[0]); o[5] = f2bf(b[1]); o[6] = f2bf(b[2]); o[7] = f2bf(b[3]);
    ((ushort8*)xb)[idx] = o;
}

// ---------------------------------------------------------------------------
// Kernel 3: GEMM  C = A(bf16)[M,K] * B^T(bf16)[N,K] + bias, C fp32 [M,N]
// 128x128 tile, BK=64, 4 waves (2x2 of 64x64), 32x32x16 bf16 MFMA (2x2/wave),
// global_load_lds width=16 staging with XOR chunk swizzle on the global side.
// ---------------------------------------------------------------------------
__device__ __forceinline__ void gload16(const void* g, void* l) {
    __builtin_amdgcn_global_load_lds(
        (const __attribute__((address_space(1))) void*)g,
        (__attribute__((address_space(3))) void*)l,
        16, 0, 0);
}

__launch_bounds__(256)
__global__ void gemm_bias(const unsigned short* __restrict__ A,   // [M,K] bf16
                          const unsigned short* __restrict__ B,   // [N,K] bf16 (=W^T)
                          const float* __restrict__ bias,
                          float* __restrict__ C) {
    __shared__ __align__(16) unsigned short As[BM * BK];   // 16 KB, swizzled
    __shared__ __align__(16) unsigned short Bs[BN * BK];   // 16 KB, swizzled

    const int tid  = threadIdx.x;
    const int w    = tid >> 6;       // wave 0..3
    const int lane = tid & 63;

    // XCD-aware swizzle: xcd = id&7 owns n-blocks xcd*4 .. xcd*4+3 (4 MB of B
    // = one XCD L2); m streams, 4 n-blocks per A-panel co-resident.
    const int id    = blockIdx.x;
    const int xcd   = id & 7;
    const int local = id >> 3;
    const int n0 = (xcd * 4 + (local & 3)) * BN;
    const int m0 = (local >> 2) * BM;

    // staging: per instruction s (0..3 per wave), rows 8*(w*4+s)..+8
    const int srow   = lane >> 3;            // row within 8-row group
    const int schunk = (lane & 7) ^ srow;    // swizzled global 16B-chunk

    // fragment indices (32x32x16): A[m=lane&31][k=(lane>>5)*8+j]
    const int ln31 = lane & 31;
    const int hl   = lane >> 5;              // 0..1
    const int wm = (w & 1) * 64;
    const int wn = (w >> 1) * 64;

    floatx16 acc[2][2];
#pragma unroll
    for (int i = 0; i < 2; ++i)
#pragma unroll
        for (int j = 0; j < 2; ++j)
            acc[i][j] = (floatx16)(0.0f);

    for (int k0 = 0; k0 < K_TOT; k0 += BK) {
#pragma unroll
        for (int s = 0; s < 4; ++s) {
            const int g = w * 4 + s;             // 8-row group 0..15
            const int r = g * 8 + srow;          // tile-local row 0..127
            gload16(A + (size_t)(m0 + r) * K_TOT + k0 + schunk * 8,
                    (char*)As + g * 1024);
            gload16(B + (size_t)(n0 + r) * K_TOT + k0 + schunk * 8,
                    (char*)Bs + g * 1024);
        }
        __syncthreads();

#pragma unroll
        for (int ks = 0; ks < 4; ++ks) {         // 4 k-steps of 16
            short8 af[2], bfr[2];
#pragma unroll
            for (int i = 0; i < 2; ++i) {
                const int ra = wm + i * 32 + ln31;
                const int ca = (ks * 2 + hl) ^ (ra & 7);
                af[i]  = *(const short8*)((const char*)As + ra * 128 + ca * 16);
                const int rb = wn + i * 32 + ln31;
                const int cb = (ks * 2 + hl) ^ (rb & 7);
                bfr[i] = *(const short8*)((const char*)Bs + rb * 128 + cb * 16);
            }
#pragma unroll
            for (int i = 0; i < 2; ++i)
#pragma unroll
                for (int j = 0; j < 2; ++j)
                    acc[i][j] = __builtin_amdgcn_mfma_f32_32x32x16_bf16(
                        af[i], bfr[j], acc[i][j], 0, 0, 0);
        }
        __syncthreads();
    }

    // epilogue: C/D layout col = lane&31, row = (reg&3) + 8*(reg>>2) + 4*hl
#pragma unroll
    for (int j = 0; j < 2; ++j) {
        const int col = n0 + wn + j * 32 + ln31;
        const float bv = bias[col];
#pragma unroll
        for (int i = 0; i < 2; ++i) {
            const int rowbase = m0 + wm + i * 32 + 4 * hl;
#pragma unroll
            for (int reg = 0; reg < 16; ++reg) {
                const int row = rowbase + (reg & 3) + 8 * (reg >> 2);
                C[(size_t)row * N_TOT + col] = acc[i][j][reg] + bv;
            }
        }
    }
}

// ---------------------------------------------------------------------------
extern "C" void kernel_launch(void* const* d_in, const int* in_sizes, int n_in,
                              void* d_out, int out_size, void* d_ws, size_t ws_size,
                              hipStream_t stream) {
    const float* x    = (const float*)d_in[0];
    const float* L0   = (const float*)d_in[1];
    const float* R0   = (const float*)d_in[2];
    const float* L1   = (const float*)d_in[3];
    const float* R1   = (const float*)d_in[4];
    const float* L2   = (const float*)d_in[5];
    const float* R2   = (const float*)d_in[6];
    const float* bias = (const float*)d_in[7];
    float* out = (float*)d_out;

    unsigned short* xb = (unsigned short*)d_ws;                                  // 134 MB
    unsigned short* wt = (unsigned short*)((char*)d_ws + (size_t)134217728);     // 33.5 MB

    build_wt<<<dim3((N_TOT * K_TOT) / 256), dim3(256), 0, stream>>>(L0, R0, L1, R1, L2, R2, wt);
    convert_x<<<dim3((M_TOT * K_TOT) / (256 * 8)), dim3(256), 0, stream>>>(x, xb);
    gemm_bias<<<dim3((M_TOT / BM) * (N_TOT / BN)), dim3(256), 0, stream>>>(xb, wt, bias, out);
}